// Round 6
// baseline (430.216 us; speedup 1.0000x reference)
//
#include <hip/hip_runtime.h>
#include <hip/hip_bf16.h>
#include <hip/hip_fp16.h>

// Problem constants (match reference)
#define N_NODES 100000
#define N_EDGES 1600000
#define N_GRAPHS 128

// Counting-sort CSR build parameters (pad-8)
#define BSH 9                 // bucket = col >> 9
#define BNODES 512            // nodes per bucket
#define NB 196                // ceil(100000 / 512)
#define CAP 12288             // static per-bucket csr/record capacity (elems)
#define BLK 512               // histogram blocks
#define EPB (N_EDGES / BLK)   // 3125 edges per block (exact)
#define RECMAX 10240          // max records per bucket held in LDS

#define SPLIT 4               // pooling blocks per graph

// Two-half gather tables: half p holds channels [p*32, p*32+32), 64-B rows
// (one cache line per row). Per-phase working set 6.4 MB (~L2-resident/XCD).
#define HROWS (N_NODES + 8)   // +sentinel row (zeroed) per half

typedef __attribute__((ext_vector_type(8))) _Float16 v8h;
typedef __attribute__((ext_vector_type(4))) float v4f;
typedef __attribute__((ext_vector_type(4))) int vi4;
typedef __attribute__((ext_vector_type(2))) int vi2;
typedef __attribute__((ext_vector_type(4))) float vf4;

// unpack 2 halves packed in an int -> float2 (value-level)
__device__ __forceinline__ float2 h2f(int bits) {
    return __half22float2(__builtin_bit_cast(__half2, bits));
}

__device__ __forceinline__ v8h zero8h() {
    v8h z = {(_Float16)0, (_Float16)0, (_Float16)0, (_Float16)0,
             (_Float16)0, (_Float16)0, (_Float16)0, (_Float16)0};
    return z;
}

// ---------------- CSR build (no global atomics) ----------------

__global__ __launch_bounds__(256) void k_hist(const int* __restrict__ col,
                                              int* __restrict__ hist_t) {
    __shared__ int h[NB];
    const int t = threadIdx.x, b = blockIdx.x;
    for (int i = t; i < NB; i += 256) h[i] = 0;
    __syncthreads();
    const int e0 = b * EPB;
    for (int i = t; i < EPB; i += 256) atomicAdd(&h[col[e0 + i] >> BSH], 1);
    __syncthreads();
    for (int i = t; i < NB; i += 256) hist_t[i * BLK + b] = h[i];
}

__global__ __launch_bounds__(512) void k_cursors(const int* __restrict__ hist_t,
                                                 int* __restrict__ cursors,
                                                 int* __restrict__ bcnt) {
    __shared__ int s[BLK];
    const int t = threadIdx.x, bin = blockIdx.x;
    const int v = hist_t[bin * BLK + t];
    s[t] = v; __syncthreads();
    for (int off = 1; off < BLK; off <<= 1) {
        int a = (t >= off) ? s[t - off] : 0;
        __syncthreads(); s[t] += a; __syncthreads();
    }
    cursors[bin * BLK + t] = bin * CAP + s[t] - v;   // exclusive + static base
    if (t == BLK - 1) bcnt[bin] = s[t];
}

__global__ __launch_bounds__(256) void k_mid(const int* __restrict__ row,
                                             const int* __restrict__ col,
                                             const int* __restrict__ cursors,
                                             int* __restrict__ bedges) {
    __shared__ int cur[NB];
    const int t = threadIdx.x, b = blockIdx.x;
    for (int i = t; i < NB; i += 256) cur[i] = cursors[i * BLK + b];
    __syncthreads();
    const int e0 = b * EPB;
    for (int i = t; i < EPB; i += 256) {
        const int c = col[e0 + i];
        const int r = row[e0 + i];
        const int pos = atomicAdd(&cur[c >> BSH], 1);
        bedges[pos] = r | ((c & (BNODES - 1)) << 17);   // row<2^17, lcol 9 bits
    }
}

__global__ __launch_bounds__(512) void k_build(const int* __restrict__ bedges,
                                               const int* __restrict__ bcnt,
                                               int* __restrict__ csr,
                                               int* __restrict__ offs,
                                               int* __restrict__ deg_c,
                                               float* __restrict__ dinv) {
    __shared__ int rec[RECMAX];
    __shared__ int deg[BNODES];
    __shared__ int offx[BNODES];
    __shared__ int cur[BNODES];
    const int t = threadIdx.x, bin = blockIdx.x;
    const int base = bin * CAP;
    const int cnt = bcnt[bin];
    const int vb = bin << BSH;
    const int nn = min(BNODES, N_NODES - vb);
    for (int i = t; i < cnt; i += 512) rec[i] = bedges[base + i];
    deg[t] = 0;
    __syncthreads();                 // all record loads done before any csr write
    for (int i = t; i < cnt; i += 512) atomicAdd(&deg[(rec[i] >> 17) & (BNODES - 1)], 1);
    __syncthreads();
    const int d = (t < nn) ? deg[t] : 0;
    const int pd = (d + 7) & ~7;     // pad each segment to x8 (8-deep gather unroll)
    offx[t] = pd; __syncthreads();
    for (int off = 1; off < BNODES; off <<= 1) {
        int a = (t >= off) ? offx[t - off] : 0;
        __syncthreads(); offx[t] += a; __syncthreads();
    }
    const int myoff = offx[t] - pd;  // exclusive
    cur[t] = myoff;
    if (t < nn) {
        offs[vb + t] = base + myoff;
        deg_c[vb + t] = d;
        dinv[vb + t] = (d > 0) ? rsqrtf((float)d) : 0.0f;
        for (int j = d; j < pd; j++) csr[base + myoff + j] = N_NODES;  // sentinel
    }
    __syncthreads();
    for (int i = t; i < cnt; i += 512) {
        const int r = rec[i];
        const int pos = atomicAdd(&cur[(r >> 17) & (BNODES - 1)], 1);
        csr[base + pos] = r & 0x1FFFF;
    }
}

// ---------------- MFMA GEMM: H16[half][n][32] = fp16(dinv[n] * (X[n,:] @ W)) ----------
// 64-node x 64-ch tile, 4 waves. Only W in LDS (hi+lo fp16 split); A-fragments
// loaded directly from global. Output to the two-half gather-table layout.
// TIN=float: X row-major [N][CIN]. TIN=__half: X is two-half [2][N][32].

template <int CIN, typename TIN>
__global__ __launch_bounds__(256) void k_gemm(const TIN* __restrict__ X,
                                              const float* __restrict__ W,
                                              const float* __restrict__ dinv,
                                              __half* __restrict__ H16) {
    constexpr int SBK = CIN + 8;                 // padded k-extent
    __shared__ __align__(16) _Float16 sBh[64 * SBK];
    __shared__ __align__(16) _Float16 sBl[64 * SBK];
    const int t = threadIdx.x;
    const int w = t >> 6, lane = t & 63;
    const int quad = lane >> 4, l16 = lane & 15;
    const int nb = blockIdx.x * 64;

    // stage all W [CIN x 64] -> transposed hi/lo [c][k]
    for (int i = t; i < CIN * 16; i += 256) {
        const int k = i >> 4, c4 = (i & 15) * 4;
        const float4 wv = *reinterpret_cast<const float4*>(W + (size_t)k * 64 + c4);
        const float wf[4] = {wv.x, wv.y, wv.z, wv.w};
        #pragma unroll
        for (int j = 0; j < 4; j++) {
            const _Float16 hi = (_Float16)wf[j];
            sBh[(c4 + j) * SBK + k] = hi;
            sBl[(c4 + j) * SBK + k] = (_Float16)(wf[j] - (float)hi);
        }
    }
    __syncthreads();

    const int gn = nb + w * 16 + l16;            // A-fragment row for this lane
    v4f acc[4] = {};                             // [ntile]

    #pragma unroll
    for (int k0 = 0; k0 < CIN; k0 += 32) {
        const int kb = k0 + quad * 8;
        v8h afr;
        if (gn < N_NODES) {
            if constexpr (sizeof(TIN) == 2) {    // two-half layout [2][N][32]
                const int hf = kb >> 5, kin = kb & 31;
                afr = *reinterpret_cast<const v8h*>(
                    (const __half*)X + ((size_t)hf * N_NODES + gn) * 32 + kin);
            } else {
                const float4 u0 = *reinterpret_cast<const float4*>((const float*)X + (size_t)gn * CIN + kb);
                const float4 u1 = *reinterpret_cast<const float4*>((const float*)X + (size_t)gn * CIN + kb + 4);
                afr[0] = (_Float16)u0.x; afr[1] = (_Float16)u0.y;
                afr[2] = (_Float16)u0.z; afr[3] = (_Float16)u0.w;
                afr[4] = (_Float16)u1.x; afr[5] = (_Float16)u1.y;
                afr[6] = (_Float16)u1.z; afr[7] = (_Float16)u1.w;
            }
        } else {
            afr = zero8h();
        }
        v8h bh[4], bl[4];
        #pragma unroll
        for (int nt = 0; nt < 4; nt++) {
            bh[nt] = *reinterpret_cast<const v8h*>(&sBh[(nt * 16 + l16) * SBK + kb]);
            bl[nt] = *reinterpret_cast<const v8h*>(&sBl[(nt * 16 + l16) * SBK + kb]);
        }
        #pragma unroll
        for (int nt = 0; nt < 4; nt++) {
            acc[nt] = __builtin_amdgcn_mfma_f32_16x16x32_f16(afr, bh[nt], acc[nt], 0, 0, 0);
            acc[nt] = __builtin_amdgcn_mfma_f32_16x16x32_f16(afr, bl[nt], acc[nt], 0, 0, 0);
        }
    }

    // epilogue: channel c = nt*16+l16 -> half = nt>>1, col = (nt&1)*16+l16
    #pragma unroll
    for (int reg = 0; reg < 4; reg++) {
        const int node = nb + w * 16 + quad * 4 + reg;
        if (node < N_NODES) {
            const float dv = dinv[node];
            #pragma unroll
            for (int nt = 0; nt < 4; nt++)
                H16[((size_t)(nt >> 1) * HROWS + node) * 32 + (nt & 1) * 16 + l16] =
                    __float2half(acc[nt][reg] * dv);
        }
    }
}

// ---------------- propagation (two-phase, 64-B row gathers): ----------------
// Hout[p][v][32] = dinv[v]*sum_e fp32(H16[p][row_e][32]) + bias[p*32..]
// gridDim = (N_NODES/16, 2); phase p = blockIdx.y (all p=0 blocks dispatch
// first -> per-phase 6.4 MB table, ~L2-resident per XCD). Quad = 1 node;
// within a quad: cg = lane&7 (4 ch, 8 B), par = (lane>>3)&1 (edge parity).
// Each gather instr: 8 lanes x 8 B = one full 64-B row; parity pairs walk 2
// edges per int4 pair; shfl_xor(8) merges parities. NT loads on csr, NT
// stores on output (don't evict the table from L2).

template <typename TOUT>
__global__ __launch_bounds__(256) void k_prop(const __half* __restrict__ Hin,
                                              const int* __restrict__ csr,
                                              const int* __restrict__ offs,
                                              const int* __restrict__ deg_c,
                                              const float* __restrict__ dinv,
                                              const float* __restrict__ bias,
                                              TOUT* __restrict__ Hout) {
    const int wave = threadIdx.x >> 6, lane = threadIdx.x & 63;
    const int quad = lane >> 4;            // node slot within the wave
    const int q = lane & 15;
    const int cg = q & 7;                  // channel group within 32-ch half
    const int par = q >> 3;                // edge parity (0/1)
    const int p = blockIdx.y;              // half/phase
    const int v = blockIdx.x * 16 + wave * 4 + quad;   // grid exact: v < N_NODES
    const int start = offs[v];             // multiple of 8 -> 32B aligned
    const int cp = (deg_c[v] + 7) & ~7;
    const int* ep = csr + start;
    const __half* hb = Hin + (size_t)p * HROWS * 32 + cg * 4;
    float a0 = 0.f, a1 = 0.f, a2 = 0.f, a3 = 0.f;
    for (int j = 0; j < cp; j += 8) {      // per-quad trip count (exec mask)
        const vi4 q0 = __builtin_nontemporal_load(reinterpret_cast<const vi4*>(ep + j));
        const vi4 q1 = __builtin_nontemporal_load(reinterpret_cast<const vi4*>(ep + j + 4));
        const int ea = par ? q0.y : q0.x;
        const int eb = par ? q0.w : q0.z;
        const int ec = par ? q1.y : q1.x;
        const int ed = par ? q1.w : q1.z;
        const vi2 r0 = *reinterpret_cast<const vi2*>(hb + (size_t)ea * 32);
        const vi2 r1 = *reinterpret_cast<const vi2*>(hb + (size_t)eb * 32);
        const vi2 r2 = *reinterpret_cast<const vi2*>(hb + (size_t)ec * 32);
        const vi2 r3 = *reinterpret_cast<const vi2*>(hb + (size_t)ed * 32);
        #define ACC(r) { \
            const float2 u = h2f(r.x); \
            const float2 w2 = h2f(r.y); \
            a0 += u.x; a1 += u.y; a2 += w2.x; a3 += w2.y; }
        ACC(r0) ACC(r1) ACC(r2) ACC(r3)
        #undef ACC
    }
    // merge edge parities (lanes q and q^8 are the same quad)
    a0 += __shfl_xor(a0, 8); a1 += __shfl_xor(a1, 8);
    a2 += __shfl_xor(a2, 8); a3 += __shfl_xor(a3, 8);
    if (par == 0) {
        const float dv = dinv[v];
        const float4 bs = *reinterpret_cast<const float4*>(bias + p * 32 + cg * 4);
        const float o0 = dv * a0 + bs.x, o1 = dv * a1 + bs.y;
        const float o2 = dv * a2 + bs.z, o3 = dv * a3 + bs.w;
        if constexpr (sizeof(TOUT) == 2) {
            vi2 pk;
            pk.x = __builtin_bit_cast(int, __floats2half2_rn(o0, o1));
            pk.y = __builtin_bit_cast(int, __floats2half2_rn(o2, o3));
            __builtin_nontemporal_store(pk,
                reinterpret_cast<vi2*>((__half*)Hout + ((size_t)p * N_NODES + v) * 32 + cg * 4));
        } else {
            vf4 o; o.x = o0; o.y = o1; o.z = o2; o.w = o3;
            __builtin_nontemporal_store(o,
                reinterpret_cast<vf4*>((float*)Hout + ((size_t)p * N_NODES + v) * 32 + cg * 4));
        }
    }
}

// ---------------- pooling: one (graph, split) block; atomic-free partials ----------------
// H is two-half fp32 [2][N][32]; lane -> (half = lane>>5, col = lane&31), so
// global channel == lane and partial/k_final layouts are unchanged.

__global__ __launch_bounds__(256) void k_pool(const float* __restrict__ H,
                                              const int* __restrict__ batch,
                                              float* __restrict__ partial) {
    const int g = blockIdx.x >> 2;           // graph
    const int s = blockIdx.x & (SPLIT - 1);  // split
    int lo = 0, hi = N_NODES;
    while (lo < hi) { int m = (lo + hi) >> 1; if (batch[m] < g) lo = m + 1; else hi = m; }
    const int a = lo;
    lo = 0; hi = N_NODES;
    while (lo < hi) { int m = (lo + hi) >> 1; if (batch[m] < g + 1) lo = m + 1; else hi = m; }
    const int b = lo;

    const int wave = threadIdx.x >> 6, lane = threadIdx.x & 63;
    const int lane16 = s * 4 + wave;         // 0..15: stride position
    const size_t sbase = (size_t)(lane >> 5) * ((size_t)N_NODES * 32) + (lane & 31);
    float ac0 = 0.f, ac1 = 0.f, ac2 = 0.f, ac3 = 0.f;
    int v = a + lane16;
    for (; v + 48 < b; v += 64) {            // 4 independent loads in flight
        ac0 += H[sbase + (size_t)v * 32];
        ac1 += H[sbase + (size_t)(v + 16) * 32];
        ac2 += H[sbase + (size_t)(v + 32) * 32];
        ac3 += H[sbase + (size_t)(v + 48) * 32];
    }
    for (; v < b; v += 16) ac0 += H[sbase + (size_t)v * 32];
    const float acc = (ac0 + ac1) + (ac2 + ac3);

    __shared__ float red[4][64];
    red[wave][lane] = acc;
    __syncthreads();
    if (wave == 0) {
        const float r = (red[0][lane] + red[1][lane]) + (red[2][lane] + red[3][lane]);
        partial[((size_t)s * N_GRAPHS + g) * 64 + lane] = r;
    }
}

__global__ void k_final(const float* __restrict__ partial, const int* __restrict__ batch,
                        const float* __restrict__ Wl, const float* __restrict__ bl,
                        float* __restrict__ out) {
    __shared__ int scnt[128];
    int t = threadIdx.x;
    int lo = 0, hi = N_NODES;
    while (lo < hi) { int mid = (lo + hi) >> 1; if (batch[mid] < t) lo = mid + 1; else hi = mid; }
    int a = lo;
    lo = 0; hi = N_NODES;
    while (lo < hi) { int mid = (lo + hi) >> 1; if (batch[mid] < t + 1) lo = mid + 1; else hi = mid; }
    scnt[t] = lo - a;
    __syncthreads();
    for (int off = 64; off > 0; off >>= 1) {
        if (t < off) scnt[t] = max(scnt[t], scnt[t + off]);
        __syncthreads();
    }
    const float nmax = (float)scnt[0];
    float s = 0.f;
    for (int c = 0; c < 64; c++) {
        float g = 0.f;
        #pragma unroll
        for (int p = 0; p < SPLIT; p++)
            g += partial[((size_t)p * N_GRAPHS + t) * 64 + c];
        s += g * Wl[c];
    }
    out[t] = s / nmax + bl[0];
}

// ---------------- launch ----------------

extern "C" void kernel_launch(void* const* d_in, const int* in_sizes, int n_in,
                              void* d_out, int out_size, void* d_ws, size_t ws_size,
                              hipStream_t stream) {
    const float* x    = (const float*)d_in[0];
    const int*   ei   = (const int*)d_in[1];     // [2, E] int32
    const int*   batch= (const int*)d_in[2];
    const float* W1 = (const float*)d_in[3];  const float* b1 = (const float*)d_in[4];
    const float* W2 = (const float*)d_in[5];  const float* b2 = (const float*)d_in[6];
    const float* W3 = (const float*)d_in[7];  const float* b3 = (const float*)d_in[8];
    const float* W4 = (const float*)d_in[9];  const float* b4 = (const float*)d_in[10];
    const float* Wl = (const float*)d_in[11]; const float* bl = (const float*)d_in[12];
    float* out = (float*)d_out;

    const int* row = ei;
    const int* col = ei + N_EDGES;

    // workspace layout (256B aligned blocks)
    char* ws = (char*)d_ws;
    size_t off = 0;
    auto alloc = [&](size_t bytes) {
        void* p = ws + off;
        off = (off + bytes + 255) & ~(size_t)255;
        return p;
    };
    int*    hist_t  = (int*)alloc((size_t)NB * BLK * 4);
    int*    cursors = (int*)alloc((size_t)NB * BLK * 4);
    int*    bcnt    = (int*)alloc(NB * 4);
    int*    bedges  = (int*)alloc((size_t)NB * CAP * 4);   // aliased by csr
    int*    csr     = bedges;                              // in-place rebuild (safe)
    int*    offs    = (int*)alloc(N_NODES * 4);
    int*    deg_c   = (int*)alloc(N_NODES * 4);
    float*  dinv    = (float*)alloc(N_NODES * 4);
    __half* h16     = (__half*)alloc((size_t)2 * HROWS * 32 * 2);     // two-half gather table
    __half* h_c     = (__half*)alloc((size_t)2 * N_NODES * 32 * 2);   // fp16 prop out (L1-3)
    float*  h_b     = (float*)alloc((size_t)2 * N_NODES * 32 * 4);    // fp32 prop out (L4)
    float*  partial = (float*)alloc((size_t)SPLIT * N_GRAPHS * 64 * 4);

    // zero the per-half sentinel rows (row N_NODES of each half, 64 B)
    (void)hipMemsetAsync(h16 + ((size_t)0 * HROWS + N_NODES) * 32, 0, 32 * 2, stream);
    (void)hipMemsetAsync(h16 + ((size_t)1 * HROWS + N_NODES) * 32, 0, 32 * 2, stream);

    // CSR build: histogram -> cursors -> bucket scatter -> per-bucket build
    k_hist<<<BLK, 256, 0, stream>>>(col, hist_t);
    k_cursors<<<NB, 512, 0, stream>>>(hist_t, cursors, bcnt);
    k_mid<<<BLK, 256, 0, stream>>>(row, col, cursors, bedges);
    k_build<<<NB, 512, 0, stream>>>(bedges, bcnt, csr, offs, deg_c, dinv);

    const int GB = (N_NODES + 63) / 64;       // 1563 gemm blocks (64-node tiles)
    const dim3 gprop(N_NODES / 16, 2);        // 6250 x 2 phases

    // layer 1: h16 = fp16(dinv * (x @ W1)) ; h_c = fp16(dinv * prop(h16) + b1)
    k_gemm<128, float><<<GB, 256, 0, stream>>>(x, W1, dinv, h16);
    k_prop<__half><<<gprop, 256, 0, stream>>>(h16, csr, offs, deg_c, dinv, b1, h_c);
    // layer 2
    k_gemm<64, __half><<<GB, 256, 0, stream>>>(h_c, W2, dinv, h16);
    k_prop<__half><<<gprop, 256, 0, stream>>>(h16, csr, offs, deg_c, dinv, b2, h_c);
    // layer 3
    k_gemm<64, __half><<<GB, 256, 0, stream>>>(h_c, W3, dinv, h16);
    k_prop<__half><<<gprop, 256, 0, stream>>>(h16, csr, offs, deg_c, dinv, b3, h_c);
    // layer 4: fp32 output for pooling
    k_gemm<64, __half><<<GB, 256, 0, stream>>>(h_c, W4, dinv, h16);
    k_prop<float><<<gprop, 256, 0, stream>>>(h16, csr, offs, deg_c, dinv, b4, h_b);

    // pooling + readout (atomic-free)
    k_pool<<<N_GRAPHS * SPLIT, 256, 0, stream>>>(h_b, batch, partial);
    k_final<<<1, 128, 0, stream>>>(partial, batch, Wl, bl, out);
}

// Round 7
// 364.166 us; speedup vs baseline: 1.1814x; 1.1814x over previous
//
#include <hip/hip_runtime.h>
#include <hip/hip_bf16.h>
#include <hip/hip_fp16.h>

// Problem constants (match reference)
#define N_NODES 100000
#define N_EDGES 1600000
#define N_GRAPHS 128

// Counting-sort CSR build parameters (pad-8)
#define BSH 9                 // bucket = col >> 9
#define BNODES 512            // nodes per bucket
#define NB 196                // ceil(100000 / 512)
#define CAP 12288             // static per-bucket csr/record capacity (elems)
#define BLK 512               // histogram blocks
#define EPB (N_EDGES / BLK)   // 3125 edges per block (exact)
#define RECMAX 10240          // max records per bucket held in LDS

#define SPLIT 4               // pooling blocks per graph

typedef __attribute__((ext_vector_type(8))) _Float16 v8h;
typedef __attribute__((ext_vector_type(4))) float v4f;
typedef __attribute__((ext_vector_type(4))) int vi4;
typedef __attribute__((ext_vector_type(2))) int vi2;
typedef __attribute__((ext_vector_type(4))) float vf4;

// unpack 2 halves packed in an int -> float2 (value-level)
__device__ __forceinline__ float2 h2f(int bits) {
    return __half22float2(__builtin_bit_cast(__half2, bits));
}

__device__ __forceinline__ v8h zero8h() {
    v8h z = {(_Float16)0, (_Float16)0, (_Float16)0, (_Float16)0,
             (_Float16)0, (_Float16)0, (_Float16)0, (_Float16)0};
    return z;
}

// ---------------- CSR build (no global atomics) ----------------

__global__ __launch_bounds__(256) void k_hist(const int* __restrict__ col,
                                              int* __restrict__ hist_t,
                                              __half* __restrict__ h16) {
    __shared__ int h[NB];
    const int t = threadIdx.x, b = blockIdx.x;
    if (b == 0 && t < 64)                      // zero gather-table sentinel row
        h16[(size_t)N_NODES * 64 + t] = __float2half(0.0f);
    for (int i = t; i < NB; i += 256) h[i] = 0;
    __syncthreads();
    const int e0 = b * EPB;
    for (int i = t; i < EPB; i += 256) atomicAdd(&h[col[e0 + i] >> BSH], 1);
    __syncthreads();
    for (int i = t; i < NB; i += 256) hist_t[i * BLK + b] = h[i];
}

__global__ __launch_bounds__(512) void k_cursors(const int* __restrict__ hist_t,
                                                 int* __restrict__ cursors,
                                                 int* __restrict__ bcnt) {
    __shared__ int s[BLK];
    const int t = threadIdx.x, bin = blockIdx.x;
    const int v = hist_t[bin * BLK + t];
    s[t] = v; __syncthreads();
    for (int off = 1; off < BLK; off <<= 1) {
        int a = (t >= off) ? s[t - off] : 0;
        __syncthreads(); s[t] += a; __syncthreads();
    }
    cursors[bin * BLK + t] = bin * CAP + s[t] - v;   // exclusive + static base
    if (t == BLK - 1) bcnt[bin] = s[t];
}

__global__ __launch_bounds__(256) void k_mid(const int* __restrict__ row,
                                             const int* __restrict__ col,
                                             const int* __restrict__ cursors,
                                             int* __restrict__ bedges) {
    __shared__ int cur[NB];
    const int t = threadIdx.x, b = blockIdx.x;
    for (int i = t; i < NB; i += 256) cur[i] = cursors[i * BLK + b];
    __syncthreads();
    const int e0 = b * EPB;
    for (int i = t; i < EPB; i += 256) {
        const int c = col[e0 + i];
        const int r = row[e0 + i];
        const int pos = atomicAdd(&cur[c >> BSH], 1);
        bedges[pos] = r | ((c & (BNODES - 1)) << 17);   // row<2^17, lcol 9 bits
    }
}

__global__ __launch_bounds__(512) void k_build(const int* __restrict__ bedges,
                                               const int* __restrict__ bcnt,
                                               int* __restrict__ csr,
                                               int* __restrict__ offs,
                                               int* __restrict__ deg_c,
                                               float* __restrict__ dinv) {
    __shared__ int rec[RECMAX];
    __shared__ int deg[BNODES];
    __shared__ int offx[BNODES];
    __shared__ int cur[BNODES];
    const int t = threadIdx.x, bin = blockIdx.x;
    const int base = bin * CAP;
    const int cnt = bcnt[bin];
    const int vb = bin << BSH;
    const int nn = min(BNODES, N_NODES - vb);
    for (int i = t; i < cnt; i += 512) rec[i] = bedges[base + i];
    deg[t] = 0;
    __syncthreads();                 // all record loads done before any csr write
    for (int i = t; i < cnt; i += 512) atomicAdd(&deg[(rec[i] >> 17) & (BNODES - 1)], 1);
    __syncthreads();
    const int d = (t < nn) ? deg[t] : 0;
    const int pd = (d + 7) & ~7;     // pad each segment to x8 (8-edge gather rounds)
    offx[t] = pd; __syncthreads();
    for (int off = 1; off < BNODES; off <<= 1) {
        int a = (t >= off) ? offx[t - off] : 0;
        __syncthreads(); offx[t] += a; __syncthreads();
    }
    const int myoff = offx[t] - pd;  // exclusive
    cur[t] = myoff;
    if (t < nn) {
        offs[vb + t] = base + myoff;
        deg_c[vb + t] = d;
        dinv[vb + t] = (d > 0) ? rsqrtf((float)d) : 0.0f;
        for (int j = d; j < pd; j++) csr[base + myoff + j] = N_NODES;  // sentinel
    }
    __syncthreads();
    for (int i = t; i < cnt; i += 512) {
        const int r = rec[i];
        const int pos = atomicAdd(&cur[(r >> 17) & (BNODES - 1)], 1);
        csr[base + pos] = r & 0x1FFFF;
    }
}

// ---------------- MFMA GEMM: H16[n][64] = fp16(dinv[n] * (X[n,:] @ W)) ----------------
// 64-node x 64-ch tile, 4 waves. Only W in LDS (hi+lo fp16 split); A-fragments
// loaded directly from global (L2/L3-warm). One barrier, 1563 blocks.

template <int CIN, typename TIN>
__global__ __launch_bounds__(256) void k_gemm(const TIN* __restrict__ X,
                                              const float* __restrict__ W,
                                              const float* __restrict__ dinv,
                                              __half* __restrict__ H16) {
    constexpr int SBK = CIN + 8;                 // padded k-extent
    __shared__ __align__(16) _Float16 sBh[64 * SBK];
    __shared__ __align__(16) _Float16 sBl[64 * SBK];
    const int t = threadIdx.x;
    const int w = t >> 6, lane = t & 63;
    const int quad = lane >> 4, l16 = lane & 15;
    const int nb = blockIdx.x * 64;

    // stage all W [CIN x 64] -> transposed hi/lo [c][k]
    for (int i = t; i < CIN * 16; i += 256) {
        const int k = i >> 4, c4 = (i & 15) * 4;
        const float4 wv = *reinterpret_cast<const float4*>(W + (size_t)k * 64 + c4);
        const float wf[4] = {wv.x, wv.y, wv.z, wv.w};
        #pragma unroll
        for (int j = 0; j < 4; j++) {
            const _Float16 hi = (_Float16)wf[j];
            sBh[(c4 + j) * SBK + k] = hi;
            sBl[(c4 + j) * SBK + k] = (_Float16)(wf[j] - (float)hi);
        }
    }
    __syncthreads();

    const int gn = nb + w * 16 + l16;            // A-fragment row for this lane
    v4f acc[4] = {};                             // [ntile]

    #pragma unroll
    for (int k0 = 0; k0 < CIN; k0 += 32) {
        const int kb = k0 + quad * 8;
        v8h afr;
        if (gn < N_NODES) {
            if constexpr (sizeof(TIN) == 2) {
                afr = *reinterpret_cast<const v8h*>((const __half*)X + (size_t)gn * CIN + kb);
            } else {
                const float4 u0 = *reinterpret_cast<const float4*>((const float*)X + (size_t)gn * CIN + kb);
                const float4 u1 = *reinterpret_cast<const float4*>((const float*)X + (size_t)gn * CIN + kb + 4);
                afr[0] = (_Float16)u0.x; afr[1] = (_Float16)u0.y;
                afr[2] = (_Float16)u0.z; afr[3] = (_Float16)u0.w;
                afr[4] = (_Float16)u1.x; afr[5] = (_Float16)u1.y;
                afr[6] = (_Float16)u1.z; afr[7] = (_Float16)u1.w;
            }
        } else {
            afr = zero8h();
        }
        v8h bh[4], bl[4];
        #pragma unroll
        for (int nt = 0; nt < 4; nt++) {
            bh[nt] = *reinterpret_cast<const v8h*>(&sBh[(nt * 16 + l16) * SBK + kb]);
            bl[nt] = *reinterpret_cast<const v8h*>(&sBl[(nt * 16 + l16) * SBK + kb]);
        }
        #pragma unroll
        for (int nt = 0; nt < 4; nt++) {
            acc[nt] = __builtin_amdgcn_mfma_f32_16x16x32_f16(afr, bh[nt], acc[nt], 0, 0, 0);
            acc[nt] = __builtin_amdgcn_mfma_f32_16x16x32_f16(afr, bl[nt], acc[nt], 0, 0, 0);
        }
    }

    // epilogue: D row = quad*4+reg, col = l16
    #pragma unroll
    for (int reg = 0; reg < 4; reg++) {
        const int node = nb + w * 16 + quad * 4 + reg;
        if (node < N_NODES) {
            const float dv = dinv[node];
            #pragma unroll
            for (int nt = 0; nt < 4; nt++)
                H16[(size_t)node * 64 + nt * 16 + l16] =
                    __float2half(acc[nt][reg] * dv);
        }
    }
}

// ---------------- propagation: Hout[v] = dinv[v] * sum_e fp32(H16[row_e]) + bias ------
// 4 nodes/wave (quads). Within a quad: parity par = (lane>>3)&1 picks alternate
// edges; cl = lane&7 owns 8 channels (16 B). One gather instr = 8 rows (2 per
// quad) x 2 lines — half the instructions of the 8 B-lane version, same line
// count. 4-round unroll covers 8 edges/quad/iter. shfl_xor(8) merges parities.
// NT loads on csr; NT stores on output (keep the table's L2 lines hot).

template <typename TOUT>
__global__ __launch_bounds__(256) void k_prop(const __half* __restrict__ Hin,
                                              const int* __restrict__ csr,
                                              const int* __restrict__ offs,
                                              const int* __restrict__ deg_c,
                                              const float* __restrict__ dinv,
                                              const float* __restrict__ bias,
                                              TOUT* __restrict__ Hout) {
    const int wave = threadIdx.x >> 6, lane = threadIdx.x & 63;
    const int quad = lane >> 4;            // node slot within the wave
    const int par = (lane >> 3) & 1;       // edge parity
    const int cl = lane & 7;               // channel group: channels 8cl..8cl+7 (16 B)
    const int v = blockIdx.x * 16 + wave * 4 + quad;   // grid exact: v < N_NODES
    const int start = offs[v];             // multiple of 8 -> 32B aligned
    const int cp = (deg_c[v] + 7) & ~7;
    const int* ep = csr + start;
    const __half* hb = Hin + cl * 8;
    float a0 = 0.f, a1 = 0.f, a2 = 0.f, a3 = 0.f;
    float a4 = 0.f, a5 = 0.f, a6 = 0.f, a7 = 0.f;
    for (int j = 0; j < cp; j += 8) {      // per-quad trip count (exec mask)
        const vi4 q0 = __builtin_nontemporal_load(reinterpret_cast<const vi4*>(ep + j));
        const vi4 q1 = __builtin_nontemporal_load(reinterpret_cast<const vi4*>(ep + j + 4));
        const int ea = par ? q0.y : q0.x;
        const int eb = par ? q0.w : q0.z;
        const int ec = par ? q1.y : q1.x;
        const int ed = par ? q1.w : q1.z;
        const vi4 r0 = *reinterpret_cast<const vi4*>(hb + (size_t)ea * 64);
        const vi4 r1 = *reinterpret_cast<const vi4*>(hb + (size_t)eb * 64);
        const vi4 r2 = *reinterpret_cast<const vi4*>(hb + (size_t)ec * 64);
        const vi4 r3 = *reinterpret_cast<const vi4*>(hb + (size_t)ed * 64);
        #define ACC(r) { \
            const float2 u0 = h2f(r.x), u1 = h2f(r.y); \
            const float2 u2 = h2f(r.z), u3 = h2f(r.w); \
            a0 += u0.x; a1 += u0.y; a2 += u1.x; a3 += u1.y; \
            a4 += u2.x; a5 += u2.y; a6 += u3.x; a7 += u3.y; }
        ACC(r0) ACC(r1) ACC(r2) ACC(r3)
        #undef ACC
    }
    // merge edge parities (lanes l and l^8 share quad + channel group)
    a0 += __shfl_xor(a0, 8); a1 += __shfl_xor(a1, 8);
    a2 += __shfl_xor(a2, 8); a3 += __shfl_xor(a3, 8);
    a4 += __shfl_xor(a4, 8); a5 += __shfl_xor(a5, 8);
    a6 += __shfl_xor(a6, 8); a7 += __shfl_xor(a7, 8);
    if (par == 0) {
        const float dv = dinv[v];
        const float4 b0 = *reinterpret_cast<const float4*>(bias + cl * 8);
        const float4 b1 = *reinterpret_cast<const float4*>(bias + cl * 8 + 4);
        const float o0 = dv * a0 + b0.x, o1 = dv * a1 + b0.y;
        const float o2 = dv * a2 + b0.z, o3 = dv * a3 + b0.w;
        const float o4 = dv * a4 + b1.x, o5 = dv * a5 + b1.y;
        const float o6 = dv * a6 + b1.z, o7 = dv * a7 + b1.w;
        if constexpr (sizeof(TOUT) == 2) {
            vi4 pk;
            pk.x = __builtin_bit_cast(int, __floats2half2_rn(o0, o1));
            pk.y = __builtin_bit_cast(int, __floats2half2_rn(o2, o3));
            pk.z = __builtin_bit_cast(int, __floats2half2_rn(o4, o5));
            pk.w = __builtin_bit_cast(int, __floats2half2_rn(o6, o7));
            __builtin_nontemporal_store(pk,
                reinterpret_cast<vi4*>((__half*)Hout + (size_t)v * 64 + cl * 8));
        } else {
            vf4 olo; olo.x = o0; olo.y = o1; olo.z = o2; olo.w = o3;
            vf4 ohi; ohi.x = o4; ohi.y = o5; ohi.z = o6; ohi.w = o7;
            float* dst = (float*)Hout + (size_t)v * 64 + cl * 8;
            __builtin_nontemporal_store(olo, reinterpret_cast<vf4*>(dst));
            __builtin_nontemporal_store(ohi, reinterpret_cast<vf4*>(dst + 4));
        }
    }
}

// ---------------- pooling: one (graph, split) block; atomic-free partials ----------------

__global__ __launch_bounds__(256) void k_pool(const float* __restrict__ H,
                                              const int* __restrict__ batch,
                                              float* __restrict__ partial) {
    const int g = blockIdx.x >> 2;           // graph
    const int s = blockIdx.x & (SPLIT - 1);  // split
    int lo = 0, hi = N_NODES;
    while (lo < hi) { int m = (lo + hi) >> 1; if (batch[m] < g) lo = m + 1; else hi = m; }
    const int a = lo;
    lo = 0; hi = N_NODES;
    while (lo < hi) { int m = (lo + hi) >> 1; if (batch[m] < g + 1) lo = m + 1; else hi = m; }
    const int b = lo;

    const int wave = threadIdx.x >> 6, lane = threadIdx.x & 63;
    const int lane16 = s * 4 + wave;         // 0..15: stride position
    float ac0 = 0.f, ac1 = 0.f, ac2 = 0.f, ac3 = 0.f;
    int v = a + lane16;
    for (; v + 48 < b; v += 64) {            // 4 independent loads in flight
        ac0 += H[(size_t)v * 64 + lane];
        ac1 += H[(size_t)(v + 16) * 64 + lane];
        ac2 += H[(size_t)(v + 32) * 64 + lane];
        ac3 += H[(size_t)(v + 48) * 64 + lane];
    }
    for (; v < b; v += 16) ac0 += H[(size_t)v * 64 + lane];
    const float acc = (ac0 + ac1) + (ac2 + ac3);

    __shared__ float red[4][64];
    red[wave][lane] = acc;
    __syncthreads();
    if (wave == 0) {
        const float r = (red[0][lane] + red[1][lane]) + (red[2][lane] + red[3][lane]);
        partial[((size_t)s * N_GRAPHS + g) * 64 + lane] = r;
    }
}

// one wave per graph: lane = channel; counts recomputed per block (cheap)
__global__ __launch_bounds__(64) void k_final(const float* __restrict__ partial,
                                              const int* __restrict__ batch,
                                              const float* __restrict__ Wl,
                                              const float* __restrict__ bl,
                                              float* __restrict__ out) {
    const int g = blockIdx.x, lane = threadIdx.x;   // 128 blocks x 64 lanes
    // graph sizes: lane computes counts for graphs lane and lane+64; max-reduce
    int m = 0;
    #pragma unroll
    for (int h = 0; h < 2; h++) {
        const int gg = lane + h * 64;
        int lo = 0, hi = N_NODES;
        while (lo < hi) { int mid = (lo + hi) >> 1; if (batch[mid] < gg) lo = mid + 1; else hi = mid; }
        const int a = lo;
        lo = 0; hi = N_NODES;
        while (lo < hi) { int mid = (lo + hi) >> 1; if (batch[mid] < gg + 1) lo = mid + 1; else hi = mid; }
        m = max(m, lo - a);
    }
    #pragma unroll
    for (int off = 32; off > 0; off >>= 1) m = max(m, __shfl_xor(m, off));
    const float nmax = (float)m;

    float s = 0.f;
    #pragma unroll
    for (int p = 0; p < SPLIT; p++)
        s += partial[((size_t)p * N_GRAPHS + g) * 64 + lane];
    s *= Wl[lane];
    #pragma unroll
    for (int off = 32; off > 0; off >>= 1) s += __shfl_xor(s, off);
    if (lane == 0) out[g] = s / nmax + bl[0];
}

// ---------------- launch ----------------

extern "C" void kernel_launch(void* const* d_in, const int* in_sizes, int n_in,
                              void* d_out, int out_size, void* d_ws, size_t ws_size,
                              hipStream_t stream) {
    const float* x    = (const float*)d_in[0];
    const int*   ei   = (const int*)d_in[1];     // [2, E] int32
    const int*   batch= (const int*)d_in[2];
    const float* W1 = (const float*)d_in[3];  const float* b1 = (const float*)d_in[4];
    const float* W2 = (const float*)d_in[5];  const float* b2 = (const float*)d_in[6];
    const float* W3 = (const float*)d_in[7];  const float* b3 = (const float*)d_in[8];
    const float* W4 = (const float*)d_in[9];  const float* b4 = (const float*)d_in[10];
    const float* Wl = (const float*)d_in[11]; const float* bl = (const float*)d_in[12];
    float* out = (float*)d_out;

    const int* row = ei;
    const int* col = ei + N_EDGES;

    // workspace layout (256B aligned blocks)
    char* ws = (char*)d_ws;
    size_t off = 0;
    auto alloc = [&](size_t bytes) {
        void* p = ws + off;
        off = (off + bytes + 255) & ~(size_t)255;
        return p;
    };
    int*    hist_t  = (int*)alloc((size_t)NB * BLK * 4);
    int*    cursors = (int*)alloc((size_t)NB * BLK * 4);
    int*    bcnt    = (int*)alloc(NB * 4);
    int*    bedges  = (int*)alloc((size_t)NB * CAP * 4);   // aliased by csr
    int*    csr     = bedges;                              // in-place rebuild (safe)
    int*    offs    = (int*)alloc(N_NODES * 4);
    int*    deg_c   = (int*)alloc(N_NODES * 4);
    float*  dinv    = (float*)alloc(N_NODES * 4);
    __half* h16     = (__half*)alloc((size_t)(N_NODES + 1) * 64 * 2);  // gather table (+1 zero row)
    __half* h_c     = (__half*)alloc((size_t)N_NODES * 64 * 2);        // fp16 prop output (layers 1-3)
    float*  h_b     = (float*)alloc((size_t)N_NODES * 64 * 4);         // fp32 prop output (layer 4)
    float*  partial = (float*)alloc((size_t)SPLIT * N_GRAPHS * 64 * 4);

    // CSR build: histogram (also zeroes h16 sentinel) -> cursors -> scatter -> build
    k_hist<<<BLK, 256, 0, stream>>>(col, hist_t, h16);
    k_cursors<<<NB, 512, 0, stream>>>(hist_t, cursors, bcnt);
    k_mid<<<BLK, 256, 0, stream>>>(row, col, cursors, bedges);
    k_build<<<NB, 512, 0, stream>>>(bedges, bcnt, csr, offs, deg_c, dinv);

    const int GB = (N_NODES + 63) / 64;     // 1563 gemm blocks (64-node tiles)
    const int PB = N_NODES / 16;            // 6250 prop blocks (16 nodes/block)

    // layer 1: h16 = fp16(dinv * (x @ W1)) ; h_c = fp16(dinv * prop(h16) + b1)
    k_gemm<128, float><<<GB, 256, 0, stream>>>(x, W1, dinv, h16);
    k_prop<__half><<<PB, 256, 0, stream>>>(h16, csr, offs, deg_c, dinv, b1, h_c);
    // layer 2
    k_gemm<64, __half><<<GB, 256, 0, stream>>>(h_c, W2, dinv, h16);
    k_prop<__half><<<PB, 256, 0, stream>>>(h16, csr, offs, deg_c, dinv, b2, h_c);
    // layer 3
    k_gemm<64, __half><<<GB, 256, 0, stream>>>(h_c, W3, dinv, h16);
    k_prop<__half><<<PB, 256, 0, stream>>>(h16, csr, offs, deg_c, dinv, b3, h_c);
    // layer 4: fp32 output for pooling
    k_gemm<64, __half><<<GB, 256, 0, stream>>>(h_c, W4, dinv, h16);
    k_prop<float><<<PB, 256, 0, stream>>>(h16, csr, offs, deg_c, dinv, b4, h_b);

    // pooling + readout (atomic-free)
    k_pool<<<N_GRAPHS * SPLIT, 256, 0, stream>>>(h_b, batch, partial);
    k_final<<<N_GRAPHS, 64, 0, stream>>>(partial, batch, Wl, bl, out);
}